// Round 13
// baseline (387.676 us; speedup 1.0000x reference)
//
#include <hip/hip_runtime.h>

#define N_NODES 50000
#define N_EDGES 800000
#define N_GRAPHS 256
#define D_IN 256
#define D_HID 512
#define MPAD 50048     // 391 * 128, padded row/K count
#define NKS 64         // K-splits for the z-GEMM
#define KSPAN 800      // 25 * 32 k per split; 64*800 >= 50048
#define CSR_STRIDE 64  // padded CSR row capacity; P(deg>64) ~ 1e-20 for Poisson(16)

// k_prep block ranges: FILL | WT | COUNTS | CONV | ZZERO
#define NB_FILL 391    // ceil(100000/256) ; 8 edges/thread
#define NB_WT 512      // 131072/256
#define NB_CONV 6250   // 1,600,000 / 256 ; 8 floats/thread
#define NB_ZZ 6256     // 12,812,288 floats / 8 / 256 ; zero z
#define NB_PREP (NB_FILL + NB_WT + 1 + NB_CONV + NB_ZZ)

// k_aggscat: 12500 agg + 831 scatter blocks, scatter INTERLEAVED every 16th
#define NB_AGG 12500
#define NB_SCAT 831
#define NB_AGGTOT (NB_AGG + NB_SCAT)  // 13331; scatter at b&15==15 for b<13296

typedef __attribute__((ext_vector_type(8))) short bf16x8;
typedef __attribute__((ext_vector_type(4))) short bf16x4;
typedef __attribute__((ext_vector_type(8))) unsigned short u16x8;
typedef __attribute__((ext_vector_type(4))) float f32x4;

static __device__ __forceinline__ unsigned short f2bf(float f) {
  unsigned u = __float_as_uint(f);
  u += 0x7fffu + ((u >> 16) & 1u);  // round-to-nearest-even
  return (unsigned short)(u >> 16);
}
static __device__ __forceinline__ float bf2f(unsigned short h) {
  return __uint_as_float(((unsigned)h) << 16);
}

// ---------- fused prep: CSR fill + W1^T + counts/maxlen + X->bf16 + z-zero ----------
__global__ __launch_bounds__(256) void k_prep(const int* __restrict__ esrc,
                                              const int* __restrict__ edst,
                                              const float* __restrict__ W1,
                                              const float* __restrict__ x,
                                              const int* __restrict__ batch,
                                              int* __restrict__ deg, int* __restrict__ csr,
                                              unsigned short* __restrict__ wt,
                                              unsigned short* __restrict__ xb,
                                              float* __restrict__ z,
                                              int* __restrict__ counts, float* __restrict__ ml) {
  const int b = blockIdx.x, t = threadIdx.x;
  if (b < NB_FILL) {
    const int gid = b * 256 + t;
    if (gid < 100000) {
#pragma unroll
      for (int j = 0; j < 8; ++j) {
        const int e = gid + j * 100000;
        const int d = edst[e];
        const int s = esrc[e];
        const int pos = atomicAdd(&deg[d], 1);
        if (pos < CSR_STRIDE) csr[((size_t)d << 6) + pos] = s;
      }
    }
  } else if (b < NB_FILL + NB_WT) {
    const int i = (b - NB_FILL) * 256 + t;  // < 131072 exact
    const int k = i >> 9, n = i & 511;
    wt[n * 256 + k] = f2bf(W1[i]);
  } else if (b == NB_FILL + NB_WT) {
    // counts via binary search on sorted batch + maxlen
    __shared__ int sc[256];
    const int g = t;
    int lo0 = 0, hi0 = N_NODES;
    while (lo0 < hi0) { int m = (lo0 + hi0) >> 1; if (batch[m] < g) lo0 = m + 1; else hi0 = m; }
    int lo1 = lo0, hi1 = N_NODES;
    while (lo1 < hi1) { int m = (lo1 + hi1) >> 1; if (batch[m] < g + 1) lo1 = m + 1; else hi1 = m; }
    const int c = lo1 - lo0;
    counts[g] = c;
    sc[g] = c;
    __syncthreads();
    if (t < 64) {
      int m = max(max(sc[t], sc[t + 64]), max(sc[t + 128], sc[t + 192]));
#pragma unroll
      for (int off = 32; off > 0; off >>= 1) m = max(m, __shfl_xor(m, off));
      if (t == 0) *ml = (float)m;
    }
  } else if (b < NB_FILL + NB_WT + 1 + NB_CONV) {
    const int i = (b - NB_FILL - NB_WT - 1) * 256 + t;  // < 1,600,000 exact
    const float4* xp = (const float4*)x;
    float4 v0 = xp[(size_t)i * 2];
    float4 v1 = xp[(size_t)i * 2 + 1];
    u16x8 o;
    o[0] = f2bf(v0.x); o[1] = f2bf(v0.y); o[2] = f2bf(v0.z); o[3] = f2bf(v0.w);
    o[4] = f2bf(v1.x); o[5] = f2bf(v1.y); o[6] = f2bf(v1.z); o[7] = f2bf(v1.w);
    *(u16x8*)(xb + (size_t)i * 8) = o;
  } else {
    const size_t i = (size_t)(b - NB_FILL - NB_WT - 1 - NB_CONV) * 256 + t;  // < 1,601,536
    if (i * 8 < (size_t)N_GRAPHS * MPAD) {
      float4 zv = {0.f, 0.f, 0.f, 0.f};
      *(float4*)(z + i * 8) = zv;
      *(float4*)(z + i * 8 + 4) = zv;
    }
  }
}

// ---------- fused layer-1 aggregation + z-scatter (scatter interleaved 1:15) ----------
__global__ __launch_bounds__(256) void k_aggscat(const unsigned short* __restrict__ xw,
                                                 const int* __restrict__ deg,
                                                 const int* __restrict__ csr,
                                                 const int* __restrict__ esrc,
                                                 const int* __restrict__ edst,
                                                 const int* __restrict__ batch,
                                                 unsigned short* __restrict__ hout,
                                                 float* __restrict__ z) {
  const int b = blockIdx.x;
  const int tid = threadIdx.x;
  const bool is_scat = (b < 16 * NB_SCAT) && ((b & 15) == 15);
  if (!is_scat) {
    const int aid = (b < 16 * NB_SCAT) ? (b - (b >> 4)) : (b - NB_SCAT);
    const int lane = tid & 63, wid = tid >> 6;
    const int v = aid * 4 + wid;  // 12500 agg blocks * 4 waves = 50000 nodes
    const int cnt = min(deg[v], CSR_STRIDE);
    const int e0 = v << 6;
    const float dv = rsqrtf((float)(deg[v] + 1));
    const unsigned short* rowbase = xw + lane * 4;
    float a0 = 0.f, a1 = 0.f, a2 = 0.f, a3 = 0.f;
    int i = 0;
    for (; i + 8 <= cnt; i += 8) {
      int ss[8]; float ww[8]; bf16x4 tt[8];
#pragma unroll
      for (int j = 0; j < 8; ++j) ss[j] = csr[e0 + i + j];
#pragma unroll
      for (int j = 0; j < 8; ++j) ww[j] = rsqrtf((float)(deg[ss[j]] + 1));
#pragma unroll
      for (int j = 0; j < 8; ++j) tt[j] = *(const bf16x4*)(rowbase + (size_t)ss[j] * 256);
#pragma unroll
      for (int j = 0; j < 8; ++j) {
        a0 += ww[j] * bf2f((unsigned short)tt[j][0]);
        a1 += ww[j] * bf2f((unsigned short)tt[j][1]);
        a2 += ww[j] * bf2f((unsigned short)tt[j][2]);
        a3 += ww[j] * bf2f((unsigned short)tt[j][3]);
      }
    }
    for (; i + 4 <= cnt; i += 4) {
      int ss[4]; float ww[4]; bf16x4 tt[4];
#pragma unroll
      for (int j = 0; j < 4; ++j) ss[j] = csr[e0 + i + j];
#pragma unroll
      for (int j = 0; j < 4; ++j) ww[j] = rsqrtf((float)(deg[ss[j]] + 1));
#pragma unroll
      for (int j = 0; j < 4; ++j) tt[j] = *(const bf16x4*)(rowbase + (size_t)ss[j] * 256);
#pragma unroll
      for (int j = 0; j < 4; ++j) {
        a0 += ww[j] * bf2f((unsigned short)tt[j][0]);
        a1 += ww[j] * bf2f((unsigned short)tt[j][1]);
        a2 += ww[j] * bf2f((unsigned short)tt[j][2]);
        a3 += ww[j] * bf2f((unsigned short)tt[j][3]);
      }
    }
    for (; i < cnt; ++i) {
      const int s0 = csr[e0 + i];
      const float w0 = rsqrtf((float)(deg[s0] + 1));
      bf16x4 t0 = *(const bf16x4*)(rowbase + (size_t)s0 * 256);
      a0 += w0 * bf2f((unsigned short)t0[0]);
      a1 += w0 * bf2f((unsigned short)t0[1]);
      a2 += w0 * bf2f((unsigned short)t0[2]);
      a3 += w0 * bf2f((unsigned short)t0[3]);
    }
    bf16x4 sv = *(const bf16x4*)(rowbase + (size_t)v * 256);
    ushort4 st;
    st.x = f2bf(dv * (a0 + dv * bf2f((unsigned short)sv[0])));
    st.y = f2bf(dv * (a1 + dv * bf2f((unsigned short)sv[1])));
    st.z = f2bf(dv * (a2 + dv * bf2f((unsigned short)sv[2])));
    st.w = f2bf(dv * (a3 + dv * bf2f((unsigned short)sv[3])));
    *(ushort4*)(hout + (size_t)v * 256 + lane * 4) = st;
  } else {
    const int gid = (b >> 4) * 256 + tid;
    if (gid >= 212500) return;
#pragma unroll
    for (int j = 0; j < 4; ++j) {
      const int idx = gid + j * 212500;  // < 850000 = N_EDGES + N_NODES
      if (idx < N_EDGES) {
        int s = esrc[idx], v = edst[idx];
        float w = rsqrtf((float)(deg[s] + 1)) * rsqrtf((float)(deg[v] + 1));
        atomicAdd(&z[(size_t)batch[v] * MPAD + s], w);
      } else {
        int u = idx - N_EDGES;
        float du = rsqrtf((float)(deg[u] + 1));
        atomicAdd(&z[(size_t)batch[u] * MPAD + u], du * du);
      }
    }
  }
}

// ---------- GEMM1: h1t[512][MPAD] = relu(A[MPAD,256] @ Wt[512,256]^T + b1)^T ----------
// 1-D XCD-swizzled grid: the 4 n-blocks sharing an A-tile have equal bid%8.
__global__ __launch_bounds__(256) void k_gemm1(const unsigned short* __restrict__ A,
                                               const unsigned short* __restrict__ Bt,
                                               const float* __restrict__ bias,
                                               unsigned short* __restrict__ Ct) {
  constexpr int KD = 256;
  constexpr int LDR = 40;
  __shared__ unsigned short As[128 * LDR];
  __shared__ unsigned short Bs[128 * LDR];
  const int c = blockIdx.x & 7;
  const int r = blockIdx.x >> 3;
  const int n = r & 3;
  const int m = (r >> 2) * 8 + c;
  if (m >= MPAD / 128) return;
  const int m0 = m * 128;
  const int n0 = n * 128;
  const int tid = threadIdx.x;
  const int lane = tid & 63;
  const int wid = tid >> 6;
  const int wm = (wid >> 1) * 64;
  const int wn = (wid & 1) * 64;
  const int fr = lane & 15;
  const int fq = lane >> 4;
  const int sr = tid >> 2;
  const int sc = tid & 3;
  const unsigned short* gA = A + (size_t)(m0 + sr) * KD + sc * 8;
  const unsigned short* gB = Bt + (size_t)(n0 + sr) * KD + sc * 8;
  f32x4 acc[4][4] = {};
  for (int k0 = 0; k0 < KD; k0 += 32) {
    bf16x8 a0 = *(const bf16x8*)(gA + k0);
    bf16x8 a1 = *(const bf16x8*)(gA + (size_t)64 * KD + k0);
    bf16x8 b0 = *(const bf16x8*)(gB + k0);
    bf16x8 b1 = *(const bf16x8*)(gB + (size_t)64 * KD + k0);
    __syncthreads();
    *(bf16x8*)&As[sr * LDR + sc * 8] = a0;
    *(bf16x8*)&As[(sr + 64) * LDR + sc * 8] = a1;
    *(bf16x8*)&Bs[sr * LDR + sc * 8] = b0;
    *(bf16x8*)&Bs[(sr + 64) * LDR + sc * 8] = b1;
    __syncthreads();
    bf16x8 af[4], bfr[4];
#pragma unroll
    for (int i = 0; i < 4; ++i)
      af[i] = *(const bf16x8*)&As[(wm + i * 16 + fr) * LDR + fq * 8];
#pragma unroll
    for (int j = 0; j < 4; ++j)
      bfr[j] = *(const bf16x8*)&Bs[(wn + j * 16 + fr) * LDR + fq * 8];
#pragma unroll
    for (int i = 0; i < 4; ++i)
#pragma unroll
      for (int j = 0; j < 4; ++j)
        acc[i][j] = __builtin_amdgcn_mfma_f32_16x16x32_bf16(af[i], bfr[j], acc[i][j], 0, 0, 0);
  }
  float bcol[4];
#pragma unroll
  for (int j = 0; j < 4; ++j) bcol[j] = bias[n0 + wn + j * 16 + fr];
#pragma unroll
  for (int i = 0; i < 4; ++i)
#pragma unroll
    for (int j = 0; j < 4; ++j) {
      ushort4 pk;
      pk.x = f2bf(fmaxf(acc[i][j][0] + bcol[j], 0.f));
      pk.y = f2bf(fmaxf(acc[i][j][1] + bcol[j], 0.f));
      pk.z = f2bf(fmaxf(acc[i][j][2] + bcol[j], 0.f));
      pk.w = f2bf(fmaxf(acc[i][j][3] + bcol[j], 0.f));
      *(ushort4*)(Ct + (size_t)(n0 + wn + j * 16 + fr) * MPAD + (m0 + wm + i * 16 + fq * 4)) = pk;
    }
}

// ---------- z-GEMM: P[kg][256][512] = z[256, kslice](f32) @ h1t[512, kslice]^T ----------
__global__ __launch_bounds__(256) void k_zgemm(const float* __restrict__ z,
                                               const unsigned short* __restrict__ h1t,
                                               float* __restrict__ P) {
  constexpr int LDR = 40;
  __shared__ unsigned short As[128 * LDR];
  __shared__ unsigned short Bs[128 * LDR];
  const int bid = blockIdx.x;
  const int kg = bid & 63;
  const int j = bid >> 6;
  const int m0 = (j & 1) * 128;
  const int n0 = (j >> 1) * 128;
  const int kstart = kg * KSPAN;
  const int ksteps = min(KSPAN, MPAD - kstart);
  const int tid = threadIdx.x;
  const int lane = tid & 63;
  const int wid = tid >> 6;
  const int wm = (wid >> 1) * 64;
  const int wn = (wid & 1) * 64;
  const int fr = lane & 15;
  const int fq = lane >> 4;
  const int sr = tid >> 2;
  const int sc = tid & 3;
  const float* gA = z + (size_t)(m0 + sr) * MPAD + kstart + sc * 8;
  const unsigned short* gB = h1t + (size_t)(n0 + sr) * MPAD + kstart + sc * 8;
  f32x4 acc[4][4] = {};
  for (int k0 = 0; k0 < ksteps; k0 += 32) {
    float4 za0 = *(const float4*)(gA + k0);
    float4 za1 = *(const float4*)(gA + k0 + 4);
    float4 zb0 = *(const float4*)(gA + (size_t)64 * MPAD + k0);
    float4 zb1 = *(const float4*)(gA + (size_t)64 * MPAD + k0 + 4);
    bf16x8 b0 = *(const bf16x8*)(gB + k0);
    bf16x8 b1 = *(const bf16x8*)(gB + (size_t)64 * MPAD + k0);
    u16x8 a0, a1;
    a0[0] = f2bf(za0.x); a0[1] = f2bf(za0.y); a0[2] = f2bf(za0.z); a0[3] = f2bf(za0.w);
    a0[4] = f2bf(za1.x); a0[5] = f2bf(za1.y); a0[6] = f2bf(za1.z); a0[7] = f2bf(za1.w);
    a1[0] = f2bf(zb0.x); a1[1] = f2bf(zb0.y); a1[2] = f2bf(zb0.z); a1[3] = f2bf(zb0.w);
    a1[4] = f2bf(zb1.x); a1[5] = f2bf(zb1.y); a1[6] = f2bf(zb1.z); a1[7] = f2bf(zb1.w);
    __syncthreads();
    *(u16x8*)&As[sr * LDR + sc * 8] = a0;
    *(u16x8*)&As[(sr + 64) * LDR + sc * 8] = a1;
    *(bf16x8*)&Bs[sr * LDR + sc * 8] = b0;
    *(bf16x8*)&Bs[(sr + 64) * LDR + sc * 8] = b1;
    __syncthreads();
    bf16x8 af[4], bfr[4];
#pragma unroll
    for (int i = 0; i < 4; ++i)
      af[i] = *(const bf16x8*)&As[(wm + i * 16 + fr) * LDR + fq * 8];
#pragma unroll
    for (int jj = 0; jj < 4; ++jj)
      bfr[jj] = *(const bf16x8*)&Bs[(wn + jj * 16 + fr) * LDR + fq * 8];
#pragma unroll
    for (int i = 0; i < 4; ++i)
#pragma unroll
      for (int jj = 0; jj < 4; ++jj)
        acc[i][jj] = __builtin_amdgcn_mfma_f32_16x16x32_bf16(af[i], bfr[jj], acc[i][jj], 0, 0, 0);
  }
  float* Pp = P + (size_t)kg * (N_GRAPHS * 512);
#pragma unroll
  for (int i = 0; i < 4; ++i)
#pragma unroll
    for (int jj = 0; jj < 4; ++jj) {
      float* cp = Pp + (size_t)(m0 + wm + i * 16 + fq * 4) * 512 + (n0 + wn + jj * 16 + fr);
#pragma unroll
      for (int rr = 0; rr < 4; ++rr) cp[(size_t)rr * 512] = acc[i][jj][rr];
    }
}

// ---------- final: one graph per block; fused P-reduce + S@W2 + tanh ----------
__global__ __launch_bounds__(256) void k_final(const float* __restrict__ P,
                                               const float* __restrict__ W2,
                                               const float* __restrict__ b2,
                                               const int* __restrict__ counts,
                                               const float* __restrict__ mlp,
                                               float* __restrict__ out) {
  __shared__ float sS[512];
  const int g = blockIdx.x;
  const int tid = threadIdx.x;
  {
    float s0 = 0.f, s1 = 0.f;
    const float* Pg = P + (size_t)g * 512 + tid * 2;
#pragma unroll 8
    for (int b = 0; b < NKS; ++b) {
      float2 v = *(const float2*)(Pg + (size_t)b * (N_GRAPHS * 512));
      s0 += v.x;
      s1 += v.y;
    }
    sS[tid * 2] = s0;
    sS[tid * 2 + 1] = s1;
  }
  __syncthreads();
  const int n = tid * 2;
  float a0 = 0.f, a1 = 0.f;
#pragma unroll 8
  for (int k = 0; k < 512; ++k) {
    float2 w = *(const float2*)&W2[(size_t)k * 512 + n];
    float s = sS[k];
    a0 += s * w.x;
    a1 += s * w.y;
  }
  const float inv_ml = 1.f / mlp[0];
  const float2 bb = *(const float2*)&b2[n];
  const float c = (float)counts[g];
  out[(size_t)g * 512 + n] = tanhf((a0 + c * bb.x) * inv_ml);
  out[(size_t)g * 512 + n + 1] = tanhf((a1 + c * bb.y) * inv_ml);
}

// ---------- launch ----------

extern "C" void kernel_launch(void* const* d_in, const int* in_sizes, int n_in,
                              void* d_out, int out_size, void* d_ws, size_t ws_size,
                              hipStream_t stream) {
  (void)in_sizes; (void)n_in; (void)out_size; (void)ws_size;
  const float* x = (const float*)d_in[0];
  const float* W1 = (const float*)d_in[1];
  const float* b1 = (const float*)d_in[2];
  const float* W2 = (const float*)d_in[3];
  const float* b2 = (const float*)d_in[4];
  const int* ei = (const int*)d_in[5];
  const int* batch = (const int*)d_in[6];
  const int* esrc = ei;
  const int* edst = ei + N_EDGES;
  float* out = (float*)d_out;

  char* p = (char*)d_ws;
  auto alloc = [&](size_t bytes) {
    char* r = p;
    p += (bytes + 255) & ~(size_t)255;
    return r;
  };

  // region0: xb (25.6MB) + ag1 (25.6MB); P (33.55MB) re-aliases it after gemm1
  const size_t SZ_REGION0 = (size_t)25600000 + 25624576;
  char* region0 = alloc(SZ_REGION0);
  unsigned short* xb = (unsigned short*)region0;                       // [50000][256] bf16
  unsigned short* ag1 = (unsigned short*)(region0 + 25600000);         // [MPAD][256] bf16
  float* P = (float*)region0;                                          // [NKS][256][512] f32 (after agg/gemm1)
  float* z = (float*)alloc((size_t)N_GRAPHS * MPAD * 4);               // [256][MPAD] f32, dedicated
  unsigned short* h1t = (unsigned short*)alloc((size_t)MPAD * D_HID * 2);  // [512][MPAD] bf16
  unsigned short* wt = (unsigned short*)alloc((size_t)512 * 256 * 2);
  int* deg = (int*)alloc((size_t)N_NODES * 4);
  int* csr = (int*)alloc((size_t)N_NODES * CSR_STRIDE * 4);            // padded CSR, 12.8 MB
  int* counts = (int*)alloc(256 * 4);
  float* ml = (float*)alloc(256);

  hipMemsetAsync(deg, 0, (size_t)N_NODES * 4, stream);
  // zero ag1 pad rows (region0 holds stale P data from the previous replay)
  hipMemsetAsync((char*)ag1 + (size_t)N_NODES * D_IN * 2, 0,
                 (size_t)(MPAD - N_NODES) * D_IN * 2, stream);

  // prep: CSR fill (atomic long pole) + W1^T + counts + X->bf16 + z-zero (backfill)
  k_prep<<<NB_PREP, 256, 0, stream>>>(esrc, edst, W1, x, batch, deg, csr, wt, xb, z, counts, ml);
  // layer-1 aggregation with z-scatter blocks interleaved 1:15 (true co-execution)
  k_aggscat<<<NB_AGGTOT, 256, 0, stream>>>(xb, deg, csr, esrc, edst, batch, ag1, z);
  k_gemm1<<<1568, 256, 0, stream>>>(ag1, wt, b1, h1t);
  k_zgemm<<<512, 256, 0, stream>>>(z, h1t, P);
  k_final<<<N_GRAPHS, 256, 0, stream>>>(P, W2, b2, counts, ml, out);
}

// Round 14
// 247.334 us; speedup vs baseline: 1.5674x; 1.5674x over previous
//
#include <hip/hip_runtime.h>

#define N_NODES 50000
#define N_EDGES 800000
#define N_GRAPHS 256
#define D_IN 256
#define D_HID 512
#define MPAD 50048     // 391 * 128, padded row/K count
#define NKS 64         // K-splits for the z-GEMM
#define KSPAN 800      // 25 * 32 k per split; 64*800 >= 50048
#define CSR_STRIDE 64  // padded CSR row capacity; P(deg>64) ~ 1e-20 for Poisson(16)

// k_prep block ranges: FILL | WT | COUNTS | CONV | ZZERO
#define NB_FILL 391    // ceil(100000/256) ; 8 edges/thread
#define NB_WT 512      // 131072/256
#define NB_CONV 6250   // 1,600,000 / 256 ; 8 floats/thread
#define NB_ZZ 6256     // 12,812,288 floats / 8 / 256 ; zero z
#define NB_PREP (NB_FILL + NB_WT + 1 + NB_CONV + NB_ZZ)

#define NB_AGG 12500   // 4 waves/block * 4 nodes

// k_gemm1scat block ranges: SCAT (leads, long pole) | GEMM1
#define NB_SCAT 831    // ceil(212500/256); 4 edges/thread
#define NB_GEMM1 1568  // 392 m-tiles * 4 n-tiles (XCD-swizzled)

typedef __attribute__((ext_vector_type(8))) short bf16x8;
typedef __attribute__((ext_vector_type(4))) short bf16x4;
typedef __attribute__((ext_vector_type(8))) unsigned short u16x8;
typedef __attribute__((ext_vector_type(4))) float f32x4;

static __device__ __forceinline__ unsigned short f2bf(float f) {
  unsigned u = __float_as_uint(f);
  u += 0x7fffu + ((u >> 16) & 1u);  // round-to-nearest-even
  return (unsigned short)(u >> 16);
}
static __device__ __forceinline__ float bf2f(unsigned short h) {
  return __uint_as_float(((unsigned)h) << 16);
}

// ---------- fused prep: CSR fill + W1^T + counts/maxlen + X->bf16 + z-zero ----------
__global__ __launch_bounds__(256) void k_prep(const int* __restrict__ esrc,
                                              const int* __restrict__ edst,
                                              const float* __restrict__ W1,
                                              const float* __restrict__ x,
                                              const int* __restrict__ batch,
                                              int* __restrict__ deg, int* __restrict__ csr,
                                              unsigned short* __restrict__ wt,
                                              unsigned short* __restrict__ xb,
                                              float* __restrict__ z,
                                              int* __restrict__ counts, float* __restrict__ ml) {
  const int b = blockIdx.x, t = threadIdx.x;
  if (b < NB_FILL) {
    const int gid = b * 256 + t;
    if (gid < 100000) {
#pragma unroll
      for (int j = 0; j < 8; ++j) {
        const int e = gid + j * 100000;
        const int d = edst[e];
        const int s = esrc[e];
        const int pos = atomicAdd(&deg[d], 1);
        if (pos < CSR_STRIDE) csr[((size_t)d << 6) + pos] = s;
      }
    }
  } else if (b < NB_FILL + NB_WT) {
    const int i = (b - NB_FILL) * 256 + t;  // < 131072 exact
    const int k = i >> 9, n = i & 511;
    wt[n * 256 + k] = f2bf(W1[i]);
  } else if (b == NB_FILL + NB_WT) {
    // counts via binary search on sorted batch + maxlen
    __shared__ int sc[256];
    const int g = t;
    int lo0 = 0, hi0 = N_NODES;
    while (lo0 < hi0) { int m = (lo0 + hi0) >> 1; if (batch[m] < g) lo0 = m + 1; else hi0 = m; }
    int lo1 = lo0, hi1 = N_NODES;
    while (lo1 < hi1) { int m = (lo1 + hi1) >> 1; if (batch[m] < g + 1) lo1 = m + 1; else hi1 = m; }
    const int c = lo1 - lo0;
    counts[g] = c;
    sc[g] = c;
    __syncthreads();
    if (t < 64) {
      int m = max(max(sc[t], sc[t + 64]), max(sc[t + 128], sc[t + 192]));
#pragma unroll
      for (int off = 32; off > 0; off >>= 1) m = max(m, __shfl_xor(m, off));
      if (t == 0) *ml = (float)m;
    }
  } else if (b < NB_FILL + NB_WT + 1 + NB_CONV) {
    const int i = (b - NB_FILL - NB_WT - 1) * 256 + t;  // < 1,600,000 exact
    const float4* xp = (const float4*)x;
    float4 v0 = xp[(size_t)i * 2];
    float4 v1 = xp[(size_t)i * 2 + 1];
    u16x8 o;
    o[0] = f2bf(v0.x); o[1] = f2bf(v0.y); o[2] = f2bf(v0.z); o[3] = f2bf(v0.w);
    o[4] = f2bf(v1.x); o[5] = f2bf(v1.y); o[6] = f2bf(v1.z); o[7] = f2bf(v1.w);
    *(u16x8*)(xb + (size_t)i * 8) = o;
  } else {
    const size_t i = (size_t)(b - NB_FILL - NB_WT - 1 - NB_CONV) * 256 + t;  // < 1,601,536
    if (i * 8 < (size_t)N_GRAPHS * MPAD) {
      float4 zv = {0.f, 0.f, 0.f, 0.f};
      *(float4*)(z + i * 8) = zv;
      *(float4*)(z + i * 8 + 4) = zv;
    }
  }
}

// ---------- layer-1 aggregation: one WAVE per node, full coalesced 512B rows ----------
__global__ __launch_bounds__(256) void k_agg256(const unsigned short* __restrict__ xw,
                                                const int* __restrict__ deg,
                                                const int* __restrict__ csr,
                                                unsigned short* __restrict__ hout) {
  const int tid = threadIdx.x;
  const int lane = tid & 63, wid = tid >> 6;
  const int v = blockIdx.x * 4 + wid;  // 12500 blocks * 4 waves = 50000 nodes
  const int cnt = min(deg[v], CSR_STRIDE);
  const int e0 = v << 6;
  const float dv = rsqrtf((float)(deg[v] + 1));
  const unsigned short* rowbase = xw + lane * 4;
  float a0 = 0.f, a1 = 0.f, a2 = 0.f, a3 = 0.f;
  int i = 0;
  for (; i + 8 <= cnt; i += 8) {
    int ss[8]; float ww[8]; bf16x4 tt[8];
#pragma unroll
    for (int j = 0; j < 8; ++j) ss[j] = csr[e0 + i + j];
#pragma unroll
    for (int j = 0; j < 8; ++j) ww[j] = rsqrtf((float)(deg[ss[j]] + 1));
#pragma unroll
    for (int j = 0; j < 8; ++j) tt[j] = *(const bf16x4*)(rowbase + (size_t)ss[j] * 256);
#pragma unroll
    for (int j = 0; j < 8; ++j) {
      a0 += ww[j] * bf2f((unsigned short)tt[j][0]);
      a1 += ww[j] * bf2f((unsigned short)tt[j][1]);
      a2 += ww[j] * bf2f((unsigned short)tt[j][2]);
      a3 += ww[j] * bf2f((unsigned short)tt[j][3]);
    }
  }
  for (; i + 4 <= cnt; i += 4) {
    int ss[4]; float ww[4]; bf16x4 tt[4];
#pragma unroll
    for (int j = 0; j < 4; ++j) ss[j] = csr[e0 + i + j];
#pragma unroll
    for (int j = 0; j < 4; ++j) ww[j] = rsqrtf((float)(deg[ss[j]] + 1));
#pragma unroll
    for (int j = 0; j < 4; ++j) tt[j] = *(const bf16x4*)(rowbase + (size_t)ss[j] * 256);
#pragma unroll
    for (int j = 0; j < 4; ++j) {
      a0 += ww[j] * bf2f((unsigned short)tt[j][0]);
      a1 += ww[j] * bf2f((unsigned short)tt[j][1]);
      a2 += ww[j] * bf2f((unsigned short)tt[j][2]);
      a3 += ww[j] * bf2f((unsigned short)tt[j][3]);
    }
  }
  for (; i < cnt; ++i) {
    const int s0 = csr[e0 + i];
    const float w0 = rsqrtf((float)(deg[s0] + 1));
    bf16x4 t0 = *(const bf16x4*)(rowbase + (size_t)s0 * 256);
    a0 += w0 * bf2f((unsigned short)t0[0]);
    a1 += w0 * bf2f((unsigned short)t0[1]);
    a2 += w0 * bf2f((unsigned short)t0[2]);
    a3 += w0 * bf2f((unsigned short)t0[3]);
  }
  bf16x4 sv = *(const bf16x4*)(rowbase + (size_t)v * 256);
  ushort4 st;
  st.x = f2bf(dv * (a0 + dv * bf2f((unsigned short)sv[0])));
  st.y = f2bf(dv * (a1 + dv * bf2f((unsigned short)sv[1])));
  st.z = f2bf(dv * (a2 + dv * bf2f((unsigned short)sv[2])));
  st.w = f2bf(dv * (a3 + dv * bf2f((unsigned short)sv[3])));
  *(ushort4*)(hout + (size_t)v * 256 + lane * 4) = st;
}

// ---------- fused GEMM1 + z-scatter ----------
// SCAT blocks lead (long-pole memory-side atomics); GEMM1 (MFMA-bound) backfills.
// GEMM1: h1t[512][MPAD] = relu(A[MPAD,256] @ Wt[512,256]^T + b1)^T, XCD-swizzled.
__global__ __launch_bounds__(256) void k_gemm1scat(const unsigned short* __restrict__ A,
                                                   const unsigned short* __restrict__ Bt,
                                                   const float* __restrict__ bias,
                                                   const int* __restrict__ esrc,
                                                   const int* __restrict__ edst,
                                                   const int* __restrict__ batch,
                                                   const int* __restrict__ deg,
                                                   unsigned short* __restrict__ Ct,
                                                   float* __restrict__ z) {
  constexpr int KD = 256;
  constexpr int LDR = 40;
  __shared__ unsigned short As[128 * LDR];
  __shared__ unsigned short Bs[128 * LDR];
  const int tid = threadIdx.x;
  if (blockIdx.x < NB_SCAT) {
    const int gid = blockIdx.x * 256 + tid;
    if (gid >= 212500) return;
#pragma unroll
    for (int j = 0; j < 4; ++j) {
      const int idx = gid + j * 212500;  // < 850000 = N_EDGES + N_NODES
      if (idx < N_EDGES) {
        int s = esrc[idx], v = edst[idx];
        float w = rsqrtf((float)(deg[s] + 1)) * rsqrtf((float)(deg[v] + 1));
        atomicAdd(&z[(size_t)batch[v] * MPAD + s], w);
      } else {
        int u = idx - N_EDGES;
        float du = rsqrtf((float)(deg[u] + 1));
        atomicAdd(&z[(size_t)batch[u] * MPAD + u], du * du);
      }
    }
    return;
  }
  const int bid = blockIdx.x - NB_SCAT;
  const int c = bid & 7;
  const int r = bid >> 3;
  const int n = r & 3;
  const int m = (r >> 2) * 8 + c;
  if (m >= MPAD / 128) return;
  const int m0 = m * 128;
  const int n0 = n * 128;
  const int lane = tid & 63;
  const int wid = tid >> 6;
  const int wm = (wid >> 1) * 64;
  const int wn = (wid & 1) * 64;
  const int fr = lane & 15;
  const int fq = lane >> 4;
  const int sr = tid >> 2;
  const int sc = tid & 3;
  const unsigned short* gA = A + (size_t)(m0 + sr) * KD + sc * 8;
  const unsigned short* gB = Bt + (size_t)(n0 + sr) * KD + sc * 8;
  f32x4 acc[4][4] = {};
  for (int k0 = 0; k0 < KD; k0 += 32) {
    bf16x8 a0 = *(const bf16x8*)(gA + k0);
    bf16x8 a1 = *(const bf16x8*)(gA + (size_t)64 * KD + k0);
    bf16x8 b0 = *(const bf16x8*)(gB + k0);
    bf16x8 b1 = *(const bf16x8*)(gB + (size_t)64 * KD + k0);
    __syncthreads();
    *(bf16x8*)&As[sr * LDR + sc * 8] = a0;
    *(bf16x8*)&As[(sr + 64) * LDR + sc * 8] = a1;
    *(bf16x8*)&Bs[sr * LDR + sc * 8] = b0;
    *(bf16x8*)&Bs[(sr + 64) * LDR + sc * 8] = b1;
    __syncthreads();
    bf16x8 af[4], bfr[4];
#pragma unroll
    for (int i = 0; i < 4; ++i)
      af[i] = *(const bf16x8*)&As[(wm + i * 16 + fr) * LDR + fq * 8];
#pragma unroll
    for (int j = 0; j < 4; ++j)
      bfr[j] = *(const bf16x8*)&Bs[(wn + j * 16 + fr) * LDR + fq * 8];
#pragma unroll
    for (int i = 0; i < 4; ++i)
#pragma unroll
      for (int j = 0; j < 4; ++j)
        acc[i][j] = __builtin_amdgcn_mfma_f32_16x16x32_bf16(af[i], bfr[j], acc[i][j], 0, 0, 0);
  }
  float bcol[4];
#pragma unroll
  for (int j = 0; j < 4; ++j) bcol[j] = bias[n0 + wn + j * 16 + fr];
#pragma unroll
  for (int i = 0; i < 4; ++i)
#pragma unroll
    for (int j = 0; j < 4; ++j) {
      ushort4 pk;
      pk.x = f2bf(fmaxf(acc[i][j][0] + bcol[j], 0.f));
      pk.y = f2bf(fmaxf(acc[i][j][1] + bcol[j], 0.f));
      pk.z = f2bf(fmaxf(acc[i][j][2] + bcol[j], 0.f));
      pk.w = f2bf(fmaxf(acc[i][j][3] + bcol[j], 0.f));
      *(ushort4*)(Ct + (size_t)(n0 + wn + j * 16 + fr) * MPAD + (m0 + wm + i * 16 + fq * 4)) = pk;
    }
}

// ---------- z-GEMM: P[kg][256][512] = z[256, kslice](f32) @ h1t[512, kslice]^T ----------
__global__ __launch_bounds__(256) void k_zgemm(const float* __restrict__ z,
                                               const unsigned short* __restrict__ h1t,
                                               float* __restrict__ P) {
  constexpr int LDR = 40;
  __shared__ unsigned short As[128 * LDR];
  __shared__ unsigned short Bs[128 * LDR];
  const int bid = blockIdx.x;
  const int kg = bid & 63;
  const int j = bid >> 6;
  const int m0 = (j & 1) * 128;
  const int n0 = (j >> 1) * 128;
  const int kstart = kg * KSPAN;
  const int ksteps = min(KSPAN, MPAD - kstart);
  const int tid = threadIdx.x;
  const int lane = tid & 63;
  const int wid = tid >> 6;
  const int wm = (wid >> 1) * 64;
  const int wn = (wid & 1) * 64;
  const int fr = lane & 15;
  const int fq = lane >> 4;
  const int sr = tid >> 2;
  const int sc = tid & 3;
  const float* gA = z + (size_t)(m0 + sr) * MPAD + kstart + sc * 8;
  const unsigned short* gB = h1t + (size_t)(n0 + sr) * MPAD + kstart + sc * 8;
  f32x4 acc[4][4] = {};
  for (int k0 = 0; k0 < ksteps; k0 += 32) {
    float4 za0 = *(const float4*)(gA + k0);
    float4 za1 = *(const float4*)(gA + k0 + 4);
    float4 zb0 = *(const float4*)(gA + (size_t)64 * MPAD + k0);
    float4 zb1 = *(const float4*)(gA + (size_t)64 * MPAD + k0 + 4);
    bf16x8 b0 = *(const bf16x8*)(gB + k0);
    bf16x8 b1 = *(const bf16x8*)(gB + (size_t)64 * MPAD + k0);
    u16x8 a0, a1;
    a0[0] = f2bf(za0.x); a0[1] = f2bf(za0.y); a0[2] = f2bf(za0.z); a0[3] = f2bf(za0.w);
    a0[4] = f2bf(za1.x); a0[5] = f2bf(za1.y); a0[6] = f2bf(za1.z); a0[7] = f2bf(za1.w);
    a1[0] = f2bf(zb0.x); a1[1] = f2bf(zb0.y); a1[2] = f2bf(zb0.z); a1[3] = f2bf(zb0.w);
    a1[4] = f2bf(zb1.x); a1[5] = f2bf(zb1.y); a1[6] = f2bf(zb1.z); a1[7] = f2bf(zb1.w);
    __syncthreads();
    *(u16x8*)&As[sr * LDR + sc * 8] = a0;
    *(u16x8*)&As[(sr + 64) * LDR + sc * 8] = a1;
    *(bf16x8*)&Bs[sr * LDR + sc * 8] = b0;
    *(bf16x8*)&Bs[(sr + 64) * LDR + sc * 8] = b1;
    __syncthreads();
    bf16x8 af[4], bfr[4];
#pragma unroll
    for (int i = 0; i < 4; ++i)
      af[i] = *(const bf16x8*)&As[(wm + i * 16 + fr) * LDR + fq * 8];
#pragma unroll
    for (int jj = 0; jj < 4; ++jj)
      bfr[jj] = *(const bf16x8*)&Bs[(wn + jj * 16 + fr) * LDR + fq * 8];
#pragma unroll
    for (int i = 0; i < 4; ++i)
#pragma unroll
      for (int jj = 0; jj < 4; ++jj)
        acc[i][jj] = __builtin_amdgcn_mfma_f32_16x16x32_bf16(af[i], bfr[jj], acc[i][jj], 0, 0, 0);
  }
  float* Pp = P + (size_t)kg * (N_GRAPHS * 512);
#pragma unroll
  for (int i = 0; i < 4; ++i)
#pragma unroll
    for (int jj = 0; jj < 4; ++jj) {
      float* cp = Pp + (size_t)(m0 + wm + i * 16 + fq * 4) * 512 + (n0 + wn + jj * 16 + fr);
#pragma unroll
      for (int rr = 0; rr < 4; ++rr) cp[(size_t)rr * 512] = acc[i][jj][rr];
    }
}

// ---------- final: one graph per block; fused P-reduce + S@W2 + tanh ----------
__global__ __launch_bounds__(256) void k_final(const float* __restrict__ P,
                                               const float* __restrict__ W2,
                                               const float* __restrict__ b2,
                                               const int* __restrict__ counts,
                                               const float* __restrict__ mlp,
                                               float* __restrict__ out) {
  __shared__ float sS[512];
  const int g = blockIdx.x;
  const int tid = threadIdx.x;
  {
    float s0 = 0.f, s1 = 0.f;
    const float* Pg = P + (size_t)g * 512 + tid * 2;
#pragma unroll 8
    for (int b = 0; b < NKS; ++b) {
      float2 v = *(const float2*)(Pg + (size_t)b * (N_GRAPHS * 512));
      s0 += v.x;
      s1 += v.y;
    }
    sS[tid * 2] = s0;
    sS[tid * 2 + 1] = s1;
  }
  __syncthreads();
  const int n = tid * 2;
  float a0 = 0.f, a1 = 0.f;
#pragma unroll 8
  for (int k = 0; k < 512; ++k) {
    float2 w = *(const float2*)&W2[(size_t)k * 512 + n];
    float s = sS[k];
    a0 += s * w.x;
    a1 += s * w.y;
  }
  const float inv_ml = 1.f / mlp[0];
  const float2 bb = *(const float2*)&b2[n];
  const float c = (float)counts[g];
  out[(size_t)g * 512 + n] = tanhf((a0 + c * bb.x) * inv_ml);
  out[(size_t)g * 512 + n + 1] = tanhf((a1 + c * bb.y) * inv_ml);
}

// ---------- launch ----------

extern "C" void kernel_launch(void* const* d_in, const int* in_sizes, int n_in,
                              void* d_out, int out_size, void* d_ws, size_t ws_size,
                              hipStream_t stream) {
  (void)in_sizes; (void)n_in; (void)out_size; (void)ws_size;
  const float* x = (const float*)d_in[0];
  const float* W1 = (const float*)d_in[1];
  const float* b1 = (const float*)d_in[2];
  const float* W2 = (const float*)d_in[3];
  const float* b2 = (const float*)d_in[4];
  const int* ei = (const int*)d_in[5];
  const int* batch = (const int*)d_in[6];
  const int* esrc = ei;
  const int* edst = ei + N_EDGES;
  float* out = (float*)d_out;

  char* p = (char*)d_ws;
  auto alloc = [&](size_t bytes) {
    char* r = p;
    p += (bytes + 255) & ~(size_t)255;
    return r;
  };

  // region0: xb (25.6MB) + ag1 (25.6MB); P (33.55MB) re-aliases it after gemm1
  const size_t SZ_REGION0 = (size_t)25600000 + 25624576;
  char* region0 = alloc(SZ_REGION0);
  unsigned short* xb = (unsigned short*)region0;                       // [50000][256] bf16
  unsigned short* ag1 = (unsigned short*)(region0 + 25600000);         // [MPAD][256] bf16
  float* P = (float*)region0;                                          // [NKS][256][512] f32 (after agg/gemm1)
  float* z = (float*)alloc((size_t)N_GRAPHS * MPAD * 4);               // [256][MPAD] f32, dedicated
  unsigned short* h1t = (unsigned short*)alloc((size_t)MPAD * D_HID * 2);  // [512][MPAD] bf16
  unsigned short* wt = (unsigned short*)alloc((size_t)512 * 256 * 2);
  int* deg = (int*)alloc((size_t)N_NODES * 4);
  int* csr = (int*)alloc((size_t)N_NODES * CSR_STRIDE * 4);            // padded CSR, 12.8 MB
  int* counts = (int*)alloc(256 * 4);
  float* ml = (float*)alloc(256);

  hipMemsetAsync(deg, 0, (size_t)N_NODES * 4, stream);
  // zero ag1 pad rows (region0 holds stale P data from the previous replay)
  hipMemsetAsync((char*)ag1 + (size_t)N_NODES * D_IN * 2, 0,
                 (size_t)(MPAD - N_NODES) * D_IN * 2, stream);

  // prep: CSR fill (atomic long pole) + W1^T + counts + X->bf16 + z-zero (backfill)
  k_prep<<<NB_PREP, 256, 0, stream>>>(esrc, edst, W1, x, batch, deg, csr, wt, xb, z, counts, ml);
  // layer-1 aggregation (pure gather, best-known form)
  k_agg256<<<NB_AGG, 256, 0, stream>>>(xb, deg, csr, ag1);
  // GEMM1 (MFMA-bound) with z-scatter blocks leading (orthogonal resources)
  k_gemm1scat<<<NB_SCAT + NB_GEMM1, 256, 0, stream>>>(ag1, wt, b1, esrc, edst, batch, deg, h1t, z);
  k_zgemm<<<512, 256, 0, stream>>>(z, h1t, P);
  k_final<<<N_GRAPHS, 256, 0, stream>>>(P, W2, b2, counts, ml, out);
}